// Round 17
// baseline (2059.717 us; speedup 1.0000x reference)
//
#include <hip/hip_runtime.h>
#include <stdint.h>

static constexpr int NB    = 4;
static constexpr int NP    = 8192;
static constexpr int KK    = 20;
static constexpr int SPLIT = 4;
static constexpr int SEG   = NP / SPLIT;   // 2048 candidates per segment/wave
static constexpr int QPB   = 64;           // queries per block (one per lane)
static constexpr int TPB   = QPB * SPLIT;  // 256 threads
static constexpr int CAP   = 28;           // log capacity (entries) per thread
static constexpr int CAPP  = 29;           // padded stride (last slot = sentinel)
static constexpr int XOFF  = NB * NP * 16; // offset of idx output in d_out
static constexpr float MARGIN = 5e-4f;     // >> worst-case |screen - d_ref|

// ---- contraction-proof scalar fp32 ops (inline asm; fp-contract pragma is
// proven ineffective under hipcc: R1==R3==R4 bitwise) ----
__device__ __forceinline__ float vadd(float a, float b) {
  float r; asm("v_add_f32 %0, %1, %2" : "=v"(r) : "v"(a), "v"(b)); return r;
}
__device__ __forceinline__ float vsub(float a, float b) {
  float r; asm("v_sub_f32 %0, %1, %2" : "=v"(r) : "v"(a), "v"(b)); return r;
}
__device__ __forceinline__ float vmul(float a, float b) {
  float r; asm("v_mul_f32 %0, %1, %2" : "=v"(r) : "v"(a), "v"(b)); return r;
}
// acc += a*b as a guaranteed single FMA (BLAS micro-kernel semantics).
__device__ __forceinline__ float vfmac(float acc, float a, float b) {
  asm("v_fmac_f32 %0, %1, %2" : "+v"(acc) : "v"(a), "v"(b)); return acc;
}

// ---- fast fp32 screen dot (FMA tree; accuracy covered by MARGIN) ----
__device__ __forceinline__ float dot16v(const float4 a0, const float4 a1,
                                        const float4 a2, const float4 a3,
                                        const float4 b0, const float4 b1,
                                        const float4 b2, const float4 b3) {
  float g0 = fmaf(a3.x, b3.x, fmaf(a2.x, b2.x, fmaf(a1.x, b1.x, a0.x * b0.x)));
  float g1 = fmaf(a3.y, b3.y, fmaf(a2.y, b2.y, fmaf(a1.y, b1.y, a0.y * b0.y)));
  float g2 = fmaf(a3.z, b3.z, fmaf(a2.z, b2.z, fmaf(a1.z, b1.z, a0.z * b0.z)));
  float g3 = fmaf(a3.w, b3.w, fmaf(a2.w, b2.w, fmaf(a1.w, b1.w, a0.w * b0.w)));
  return (g0 + g1) + (g2 + g3);
}

// ---- BLAS sgemm exact dot (verified R15): single accumulator, ascending k,
// one FMA per step; acc starts at fl(a0*b0). Asm-hardened v_fmac chain. ----
__device__ __forceinline__ float dot16_ref(const float4 a0, const float4 a1,
                                           const float4 a2, const float4 a3,
                                           const float4 b0, const float4 b1,
                                           const float4 b2, const float4 b3) {
  float acc = vmul(a0.x, b0.x);
  acc = vfmac(acc, a0.y, b0.y);
  acc = vfmac(acc, a0.z, b0.z);
  acc = vfmac(acc, a0.w, b0.w);
  acc = vfmac(acc, a1.x, b1.x);
  acc = vfmac(acc, a1.y, b1.y);
  acc = vfmac(acc, a1.z, b1.z);
  acc = vfmac(acc, a1.w, b1.w);
  acc = vfmac(acc, a2.x, b2.x);
  acc = vfmac(acc, a2.y, b2.y);
  acc = vfmac(acc, a2.z, b2.z);
  acc = vfmac(acc, a2.w, b2.w);
  acc = vfmac(acc, a3.x, b3.x);
  acc = vfmac(acc, a3.y, b3.y);
  acc = vfmac(acc, a3.z, b3.z);
  acc = vfmac(acc, a3.w, b3.w);
  return acc;
}

// ---- numpy FLOAT_pairwise_sum exact xx (verified R15): npyv SSE path,
// baseline-compiled, n=16 unit stride. Asm-hardened. ----
__device__ __forceinline__ float xx16_ref(const float4 a0, const float4 a1,
                                          const float4 a2, const float4 a3) {
  float s0 = vadd(vadd(vmul(a0.x, a0.x), vmul(a2.x, a2.x)),
                  vadd(vmul(a1.x, a1.x), vmul(a3.x, a3.x)));
  float s1 = vadd(vadd(vmul(a0.y, a0.y), vmul(a2.y, a2.y)),
                  vadd(vmul(a1.y, a1.y), vmul(a3.y, a3.y)));
  float s2 = vadd(vadd(vmul(a0.z, a0.z), vmul(a2.z, a2.z)),
                  vadd(vmul(a1.z, a1.z), vmul(a3.z, a3.z)));
  float s3 = vadd(vadd(vmul(a0.w, a0.w), vmul(a2.w, a2.w)),
                  vadd(vmul(a1.w, a1.w), vmul(a3.w, a3.w)));
  return vadd(vadd(s0, s1), vadd(s2, s3));
}

// ---- reference-exact combine (verified R15) ----
__device__ __forceinline__ float dref_combine(float xxq, float dot, float xxc) {
  float t = vmul(2.0f, dot);
  float d1 = vsub(xxq, t);
  return vadd(d1, xxc);
}

__device__ __forceinline__ unsigned umin_(unsigned a, unsigned b) { return a < b ? a : b; }
__device__ __forceinline__ unsigned umax_(unsigned a, unsigned b) { return a < b ? b : a; }

__device__ __forceinline__ unsigned floatToKey(float f) {
  unsigned db = __float_as_uint(f);
  return db ^ ((unsigned)((int)db >> 31) | 0x80000000u);
}
__device__ __forceinline__ float keyToFloat(unsigned k) {
  unsigned bits = (k & 0x80000000u) ? (k ^ 0x80000000u) : ~k;
  return __uint_as_float(bits);
}

// Screen-space compaction (unchanged logic).
__device__ __forceinline__ void compactlog(unsigned long long* lg, int& wc, float& thrF) {
  unsigned ch[20];
#pragma unroll
  for (int i = 0; i < 20; ++i) ch[i] = 0xFFFFFFFFu;
  for (int i = 0; i < wc; ++i) {
    unsigned hi = (unsigned)(lg[i] >> 32);
    if (hi < ch[0]) {
#pragma unroll
      for (int j = 0; j < 19; ++j) ch[j] = umin_(ch[j], umax_(ch[j + 1], hi));
      ch[19] = umin_(ch[19], hi);
    }
  }
  const float nt = keyToFloat(ch[0]) + MARGIN;
  const unsigned kThr = floatToKey(nt);
  int w2 = 0;
  for (int i = 0; i < wc; ++i) {
    unsigned long long e = lg[i];
    if ((unsigned)(e >> 32) <= kThr) lg[w2++] = e;
  }
  wc = w2;
  thrF = nt;
}

// Prep (unchanged from R15).
__global__ __launch_bounds__(256) void knn_prep_kernel(const float* __restrict__ x,
                                                       float* __restrict__ outx,
                                                       float* __restrict__ xxf) {
  int p = blockIdx.x * 256 + threadIdx.x;  // exact grid: 32768 points
  const float4* s = reinterpret_cast<const float4*>(x) + (size_t)p * 4;
  float4* d = reinterpret_cast<float4*>(outx) + (size_t)p * 4;
  float4 v0 = s[0], v1 = s[1], v2 = s[2], v3 = s[3];
  d[0] = v0; d[1] = v1; d[2] = v2; d[3] = v3;
  xxf[p] = xx16_ref(v0, v1, v2, v3);
}

__global__ __launch_bounds__(256) void knn_main_kernel(const float* __restrict__ x,
                                                       const float* __restrict__ xxf,
                                                       float* __restrict__ oidx) {
  __shared__ unsigned long long logbuf[TPB * CAPP];  // 59392 B
  __shared__ float4 stagec[SPLIT][256];              // 16384 B (64 cand x 4 f4)
  __shared__ float  stagex[SPLIT][64];               //  1024 B -> 76.8 KB total
  const int tid  = threadIdx.x;
  const int lane = tid & 63;    // query within block
  const int seg  = tid >> 6;    // segment == wave id (wave-uniform)
  const int qg   = blockIdx.x * QPB + lane;  // global query 0..32767
  const int b    = qg >> 13;                 // batch (uniform per block)

  const float4* qp = reinterpret_cast<const float4*>(x) + (size_t)qg * 4;
  const float4 q0 = qp[0], q1 = qp[1], q2 = qp[2], q3 = qp[3];
  const float xxq = xxf[qg];

  const int sb = __builtin_amdgcn_readfirstlane(b * NP + seg * SEG);
  const float4* cb4 = reinterpret_cast<const float4*>(x) + (size_t)sb * 4;
  const float*  xxb = xxf + sb;

  float4* sc = stagec[seg];   // wave-private stage: no inter-wave sync needed
  float*  sx = stagex[seg];

  unsigned long long* mylog = logbuf + tid * CAPP;
  float thrF = __builtin_huge_valf();
  int wc = 0;

  // Coalesced VECTOR loads (vmcnt, in-order, pipelinable) -> wave-private LDS
  // stage -> broadcast ds_read compute. T14: next block's loads issued before
  // current block's compute.
  float4 r0 = cb4[lane], r1 = cb4[64 + lane], r2 = cb4[128 + lane],
         r3 = cb4[192 + lane];
  float  rx = xxb[lane];

  int nextC = 64;
#pragma unroll 1
  for (int blk = 0; blk < SEG / 64; ++blk) {
    // Stage current block (candidate-major layout identical to global).
    sc[lane] = r0; sc[64 + lane] = r1; sc[128 + lane] = r2; sc[192 + lane] = r3;
    sx[lane] = rx;
    // Early-issue next block's global loads (independent of LDS ops).
    if (blk + 1 < SEG / 64) {
      const int nb = (blk + 1) * 256;
      r0 = cb4[nb + lane];       r1 = cb4[nb + 64 + lane];
      r2 = cb4[nb + 128 + lane]; r3 = cb4[nb + 192 + lane];
      rx = xxb[(blk + 1) * 64 + lane];
    }
    const int tbase = blk * 64;
#pragma unroll 4
    for (int j = 0; j < 64; ++j) {
      const float4 c0 = sc[j * 4 + 0], c1 = sc[j * 4 + 1];
      const float4 c2 = sc[j * 4 + 2], c3 = sc[j * 4 + 3];
      const float xxc = sx[j];
      const float dot = dot16v(q0, q1, q2, q3, c0, c1, c2, c3);
      const float d   = fmaf(-2.0f, dot, xxq) + xxc;
      if (d <= thrF) {
        if (wc == CAP) compactlog(mylog, wc, thrF);   // emergency
        if (wc < CAP) {
          const unsigned fk = floatToKey(d);
          mylog[wc++] = ((unsigned long long)fk << 32) | (unsigned)(seg * SEG + tbase + j);
        }
      }
    }
    const int t = tbase + 64;
    if (t >= nextC) {
      if (wc > 20) compactlog(mylog, wc, thrF);
      int n2 = t + (t * 35) / 100;
      n2 = (n2 + 63) & ~63;
      if (n2 < t + 64) n2 = t + 64;
      nextC = n2;
    }
  }

  // --- reference-bit-exact fp32 re-keying of survivors (unchanged R15).
  const int brow = b * NP;
  for (int i = 0; i < wc; ++i) {
    const unsigned e = (unsigned)mylog[i] & 0x1FFFu;  // candidate idx 0..8191
    const float4* cp = reinterpret_cast<const float4*>(x) + (size_t)(brow + e) * 4;
    const float4 c0 = cp[0], c1 = cp[1], c2 = cp[2], c3 = cp[3];
    const float dot = dot16_ref(q0, q1, q2, q3, c0, c1, c2, c3);
    const float dref = dref_combine(xxq, dot, xxf[brow + e]);
    mylog[i] = ((unsigned long long)floatToKey(dref) << 13) | (unsigned long long)e;
  }

  // Per-thread insertion sort ascending by (d, idx).
  for (int i = 1; i < wc; ++i) {
    unsigned long long key = mylog[i];
    int j = i - 1;
    while (j >= 0 && mylog[j] > key) {
      mylog[j + 1] = mylog[j];
      --j;
    }
    mylog[j + 1] = key;
  }
  mylog[wc] = ~0ULL;  // sentinel (wc <= 28 < CAPP)
  __syncthreads();

  // 4-way merge (unchanged R15).
  if (tid < QPB) {
    const int mq = blockIdx.x * QPB + tid;
    unsigned long long h0 = logbuf[(0 * QPB + tid) * CAPP + 0];
    unsigned long long h1 = logbuf[(1 * QPB + tid) * CAPP + 0];
    unsigned long long h2 = logbuf[(2 * QPB + tid) * CAPP + 0];
    unsigned long long h3 = logbuf[(3 * QPB + tid) * CAPP + 0];
    int p0 = 1, p1 = 1, p2 = 1, p3 = 1;
    float* dst = oidx + (size_t)mq * KK;
#pragma unroll 1
    for (int r = 0; r < KK; ++r) {
      const unsigned long long m01 = (h0 < h1) ? h0 : h1;
      const unsigned long long m23 = (h2 < h3) ? h2 : h3;
      const unsigned long long m = (m01 < m23) ? m01 : m23;
      dst[r] = (float)(unsigned)(m & 0x1FFFull);
      if (m == h0)      h0 = logbuf[(0 * QPB + tid) * CAPP + (p0++)];
      else if (m == h1) h1 = logbuf[(1 * QPB + tid) * CAPP + (p1++)];
      else if (m == h2) h2 = logbuf[(2 * QPB + tid) * CAPP + (p2++)];
      else              h3 = logbuf[(3 * QPB + tid) * CAPP + (p3++)];
    }
  }
}

extern "C" void kernel_launch(void* const* d_in, const int* in_sizes, int n_in,
                              void* d_out, int out_size, void* d_ws, size_t ws_size,
                              hipStream_t stream) {
  const float* x = (const float*)d_in[0];
  float* out = (float*)d_out;
  float* xxf = (float*)d_ws;  // 32768 floats = 128 KB scratch

  hipLaunchKernelGGL(knn_prep_kernel, dim3(NB * NP / 256), dim3(256), 0, stream,
                     x, out, xxf);
  hipLaunchKernelGGL(knn_main_kernel, dim3(NB * NP / QPB), dim3(TPB), 0, stream,
                     x, xxf, out + XOFF);
}

// Round 18
// 901.681 us; speedup vs baseline: 2.2843x; 2.2843x over previous
//
#include <hip/hip_runtime.h>
#include <stdint.h>

static constexpr int NB    = 4;
static constexpr int NP    = 8192;
static constexpr int KK    = 20;
static constexpr int SPLIT = 4;
static constexpr int SEG   = NP / SPLIT;   // 2048 candidates per segment/wave
static constexpr int QPB   = 64;           // queries per block (one per lane)
static constexpr int TPB   = QPB * SPLIT;  // 256 threads
static constexpr int CAP   = 28;           // log capacity per (query,segment)
static constexpr int CAPP  = 29;           // padded stride (last slot = sentinel)
static constexpr int XOFF  = NB * NP * 16;
static constexpr float MARGIN = 5e-4f;     // >> 2x worst-case |screen - d_ref|

// ---- contraction-proof scalar fp32 ops ----
__device__ __forceinline__ float vadd(float a, float b) {
  float r; asm("v_add_f32 %0, %1, %2" : "=v"(r) : "v"(a), "v"(b)); return r;
}
__device__ __forceinline__ float vsub(float a, float b) {
  float r; asm("v_sub_f32 %0, %1, %2" : "=v"(r) : "v"(a), "v"(b)); return r;
}
__device__ __forceinline__ float vmul(float a, float b) {
  float r; asm("v_mul_f32 %0, %1, %2" : "=v"(r) : "v"(a), "v"(b)); return r;
}
__device__ __forceinline__ float vfmac(float acc, float a, float b) {
  asm("v_fmac_f32 %0, %1, %2" : "+v"(acc) : "v"(a), "v"(b)); return acc;
}

// ---- fast screen dot (tree; any order, margin covers) ----
__device__ __forceinline__ float dot16v(const float4 a0, const float4 a1,
                                        const float4 a2, const float4 a3,
                                        const float4 b0, const float4 b1,
                                        const float4 b2, const float4 b3) {
  float g0 = fmaf(a3.x, b3.x, fmaf(a2.x, b2.x, fmaf(a1.x, b1.x, a0.x * b0.x)));
  float g1 = fmaf(a3.y, b3.y, fmaf(a2.y, b2.y, fmaf(a1.y, b1.y, a0.y * b0.y)));
  float g2 = fmaf(a3.z, b3.z, fmaf(a2.z, b2.z, fmaf(a1.z, b1.z, a0.z * b0.z)));
  float g3 = fmaf(a3.w, b3.w, fmaf(a2.w, b2.w, fmaf(a1.w, b1.w, a0.w * b0.w)));
  return (g0 + g1) + (g2 + g3);
}

// ---- VERIFIED (R15) reference-exact dot: ascending-k FMA chain ----
__device__ __forceinline__ float dot16_ref(const float4 a0, const float4 a1,
                                           const float4 a2, const float4 a3,
                                           const float4 b0, const float4 b1,
                                           const float4 b2, const float4 b3) {
  float acc = vmul(a0.x, b0.x);
  acc = vfmac(acc, a0.y, b0.y);  acc = vfmac(acc, a0.z, b0.z);
  acc = vfmac(acc, a0.w, b0.w);  acc = vfmac(acc, a1.x, b1.x);
  acc = vfmac(acc, a1.y, b1.y);  acc = vfmac(acc, a1.z, b1.z);
  acc = vfmac(acc, a1.w, b1.w);  acc = vfmac(acc, a2.x, b2.x);
  acc = vfmac(acc, a2.y, b2.y);  acc = vfmac(acc, a2.z, b2.z);
  acc = vfmac(acc, a2.w, b2.w);  acc = vfmac(acc, a3.x, b3.x);
  acc = vfmac(acc, a3.y, b3.y);  acc = vfmac(acc, a3.z, b3.z);
  acc = vfmac(acc, a3.w, b3.w);
  return acc;
}

// ---- VERIFIED (R15) reference-exact xx: numpy SSE pairwise ----
__device__ __forceinline__ float xx16_ref(const float4 a0, const float4 a1,
                                          const float4 a2, const float4 a3) {
  float s0 = vadd(vadd(vmul(a0.x, a0.x), vmul(a2.x, a2.x)),
                  vadd(vmul(a1.x, a1.x), vmul(a3.x, a3.x)));
  float s1 = vadd(vadd(vmul(a0.y, a0.y), vmul(a2.y, a2.y)),
                  vadd(vmul(a1.y, a1.y), vmul(a3.y, a3.y)));
  float s2 = vadd(vadd(vmul(a0.z, a0.z), vmul(a2.z, a2.z)),
                  vadd(vmul(a1.z, a1.z), vmul(a3.z, a3.z)));
  float s3 = vadd(vadd(vmul(a0.w, a0.w), vmul(a2.w, a2.w)),
                  vadd(vmul(a1.w, a1.w), vmul(a3.w, a3.w)));
  return vadd(vadd(s0, s1), vadd(s2, s3));
}

// ---- VERIFIED (R15) reference-exact combine ----
__device__ __forceinline__ float dref_combine(float xxq, float dot, float xxc) {
  float t = vmul(2.0f, dot);
  float d1 = vsub(xxq, t);
  return vadd(d1, xxc);
}

__device__ __forceinline__ unsigned umin_(unsigned a, unsigned b) { return a < b ? a : b; }
__device__ __forceinline__ unsigned umax_(unsigned a, unsigned b) { return a < b ? b : a; }

__device__ __forceinline__ unsigned floatToKey(float f) {
  unsigned db = __float_as_uint(f);
  return db ^ ((unsigned)((int)db >> 31) | 0x80000000u);
}
__device__ __forceinline__ float keyToFloat(unsigned k) {
  unsigned bits = (k & 0x80000000u) ? (k ^ 0x80000000u) : ~k;
  return __uint_as_float(bits);
}
__device__ __forceinline__ unsigned laneRank(unsigned long long m) {
  return __builtin_amdgcn_mbcnt_hi((unsigned)(m >> 32),
         __builtin_amdgcn_mbcnt_lo((unsigned)m, 0u));
}

// Per-thread compaction (register chain over own LDS log) — R15 logic.
__device__ __forceinline__ void compactlog(unsigned long long* lg, int& wc, float& thrF) {
  unsigned ch[20];
#pragma unroll
  for (int i = 0; i < 20; ++i) ch[i] = 0xFFFFFFFFu;
  for (int i = 0; i < wc; ++i) {
    unsigned hi = (unsigned)(lg[i] >> 32);
    if (hi < ch[0]) {
#pragma unroll
      for (int j = 0; j < 19; ++j) ch[j] = umin_(ch[j], umax_(ch[j + 1], hi));
      ch[19] = umin_(ch[19], hi);
    }
  }
  const float nt = keyToFloat(ch[0]) + MARGIN;
  const unsigned kThr = floatToKey(nt);
  int w2 = 0;
  for (int i = 0; i < wc; ++i) {
    unsigned long long e = lg[i];
    if ((unsigned)(e >> 32) <= kThr) lg[w2++] = e;
  }
  wc = w2;
  thrF = nt;
}

// Single-lane emergency compact (rare; noinline keeps hot loop small).
__device__ __noinline__ void serial_compact(unsigned long long* lg, int n,
                                            unsigned* wcslot, float* thrslot) {
  unsigned ch[20];
#pragma unroll
  for (int i = 0; i < 20; ++i) ch[i] = 0xFFFFFFFFu;
  for (int i = 0; i < n; ++i) {
    unsigned hi = (unsigned)(lg[i] >> 32);
    if (hi < ch[0]) {
#pragma unroll
      for (int j = 0; j < 19; ++j) ch[j] = umin_(ch[j], umax_(ch[j + 1], hi));
      ch[19] = umin_(ch[19], hi);
    }
  }
  const float nt = keyToFloat(ch[0]) + MARGIN;
  const unsigned kThr = floatToKey(nt);
  int w2 = 0;
  for (int i = 0; i < n; ++i) {
    unsigned long long e = lg[i];
    if ((unsigned)(e >> 32) <= kThr) lg[w2++] = e;
  }
  *wcslot = (unsigned)w2;
  *thrslot = nt;
}

// Prep (unchanged, verified).
__global__ __launch_bounds__(256) void knn_prep_kernel(const float* __restrict__ x,
                                                       float* __restrict__ outx,
                                                       float* __restrict__ xxf) {
  int p = blockIdx.x * 256 + threadIdx.x;
  const float4* s = reinterpret_cast<const float4*>(x) + (size_t)p * 4;
  float4* d = reinterpret_cast<float4*>(outx) + (size_t)p * 4;
  float4 v0 = s[0], v1 = s[1], v2 = s[2], v3 = s[3];
  d[0] = v0; d[1] = v1; d[2] = v2; d[3] = v3;
  xxf[p] = xx16_ref(v0, v1, v2, v3);
}

__global__ __launch_bounds__(256) void knn_main_kernel(const float* __restrict__ x,
                                                       const float* __restrict__ xxf,
                                                       float* __restrict__ oidx) {
  __shared__ unsigned long long logbuf[TPB * CAPP];  // 59392 B
  __shared__ float    thrv[TPB];                     //  1024 B
  __shared__ unsigned wcarr[TPB];                    //  1024 B -> 60 KB total
  const int tid  = threadIdx.x;
  const int lane = tid & 63;
  const int seg  = tid >> 6;
  const int qg   = blockIdx.x * QPB + lane;
  const int b    = qg >> 13;

  const float4* qp = reinterpret_cast<const float4*>(x) + (size_t)qg * 4;
  const float4 q0 = qp[0], q1 = qp[1], q2 = qp[2], q3 = qp[3];
  const float xxq = xxf[qg];

  const int sb = __builtin_amdgcn_readfirstlane(b * NP + seg * SEG);
  const float4* cb4 = reinterpret_cast<const float4*>(x) + (size_t)sb * 4;
  const float*  xxb = xxf + sb;

  unsigned long long* mylog = logbuf + (size_t)tid * CAPP;
  float thrF = __builtin_huge_valf();
  int wc = 0;

  // ===== Phase 0: bootstrap — first 64 candidates, R15-style per-thread =====
#pragma unroll 2
  for (int t = 0; t < 64; ++t) {
    const float4 c0 = cb4[(size_t)t * 4 + 0];
    const float4 c1 = cb4[(size_t)t * 4 + 1];
    const float4 c2 = cb4[(size_t)t * 4 + 2];
    const float4 c3 = cb4[(size_t)t * 4 + 3];
    const float xxc = xxb[t];
    const float dot = dot16v(q0, q1, q2, q3, c0, c1, c2, c3);
    const float d   = fmaf(-2.0f, dot, xxq) + xxc;
    if (d <= thrF) {
      if (wc == CAP) compactlog(mylog, wc, thrF);
      if (wc < CAP) {
        mylog[wc++] = ((unsigned long long)floatToKey(d) << 32) |
                      (unsigned)(seg * SEG + t);
      }
    }
  }
  if (wc > 20) compactlog(mylog, wc, thrF);

  // Publish + global (cross-segment) checkpoint compaction.
  wcarr[tid] = (unsigned)wc;
  thrv[tid]  = thrF;
  __syncthreads();
  if (tid < QPB) {
    unsigned ch[20];
#pragma unroll
    for (int i = 0; i < 20; ++i) ch[i] = 0xFFFFFFFFu;
    int total = 0;
    for (int s = 0; s < SPLIT; ++s) {
      const int L = s * QPB + tid;
      const int n = (int)wcarr[L];
      total += n;
      for (int i = 0; i < n; ++i) {
        const unsigned hi = (unsigned)(logbuf[(size_t)L * CAPP + i] >> 32);
        if (hi < ch[0]) {
#pragma unroll
          for (int j = 0; j < 19; ++j) ch[j] = umin_(ch[j], umax_(ch[j + 1], hi));
          ch[19] = umin_(ch[19], hi);
        }
      }
    }
    if (total >= 20) {
      const float nt = keyToFloat(ch[0]) + MARGIN;
      const unsigned kThr = floatToKey(nt);
      for (int s = 0; s < SPLIT; ++s) {
        const int L = s * QPB + tid;
        const int n = (int)wcarr[L];
        int w2 = 0;
        for (int i = 0; i < n; ++i) {
          const unsigned long long e = logbuf[(size_t)L * CAPP + i];
          if ((unsigned)(e >> 32) <= kThr) logbuf[(size_t)L * CAPP + (w2++)] = e;
        }
        wcarr[L] = (unsigned)w2;
        thrv[L]  = nt;
      }
    }
  }
  __syncthreads();
  int wcv = (int)wcarr[tid];
  thrF = thrv[tid];

  // ===== Phase 1: tiles 1..31, lane=candidate, query broadcast via readlane =====
  float4 cc0, cc1, cc2, cc3; float cxx;
  {
    const size_t o = ((size_t)64 + lane) * 4;
    cc0 = cb4[o + 0]; cc1 = cb4[o + 1]; cc2 = cb4[o + 2]; cc3 = cb4[o + 3];
    cxx = xxb[64 + lane];
  }
  int nextCk = 2;
#pragma unroll 1
  for (int T = 1; T < 32; ++T) {
    if (T == nextCk) {   // block-wide global re-compaction (T = 2,4,8,16)
      wcarr[tid] = (unsigned)wcv;
      thrv[tid]  = thrF;
      __syncthreads();
      if (tid < QPB) {
        unsigned ch[20];
#pragma unroll
        for (int i = 0; i < 20; ++i) ch[i] = 0xFFFFFFFFu;
        int total = 0;
        for (int s = 0; s < SPLIT; ++s) {
          const int L = s * QPB + tid;
          const int n = (int)wcarr[L];
          total += n;
          for (int i = 0; i < n; ++i) {
            const unsigned hi = (unsigned)(logbuf[(size_t)L * CAPP + i] >> 32);
            if (hi < ch[0]) {
#pragma unroll
              for (int j = 0; j < 19; ++j) ch[j] = umin_(ch[j], umax_(ch[j + 1], hi));
              ch[19] = umin_(ch[19], hi);
            }
          }
        }
        if (total >= 20) {
          const float nt = keyToFloat(ch[0]) + MARGIN;
          const unsigned kThr = floatToKey(nt);
          for (int s = 0; s < SPLIT; ++s) {
            const int L = s * QPB + tid;
            const int n = (int)wcarr[L];
            int w2 = 0;
            for (int i = 0; i < n; ++i) {
              const unsigned long long e = logbuf[(size_t)L * CAPP + i];
              if ((unsigned)(e >> 32) <= kThr) logbuf[(size_t)L * CAPP + (w2++)] = e;
            }
            wcarr[L] = (unsigned)w2;
            thrv[L]  = nt;
          }
        }
      }
      __syncthreads();
      wcv = (int)wcarr[tid];
      thrF = thrv[tid];
      nextCk <<= 1;
    }
    // Prefetch next tile (per-lane vector loads; hidden under q-loop).
    float4 n0, n1, n2, n3; float nx;
    if (T + 1 < 32) {
      const size_t o = ((size_t)((T + 1) << 6) + lane) * 4;
      n0 = cb4[o + 0]; n1 = cb4[o + 1]; n2 = cb4[o + 2]; n3 = cb4[o + 3];
      nx = xxb[((T + 1) << 6) + lane];
    }
    const unsigned gidx = (unsigned)(seg * SEG + (T << 6) + lane);
#define RLF(v, l) __uint_as_float(__builtin_amdgcn_readlane(__float_as_uint(v), (l)))
#pragma unroll 1
    for (int q = 0; q < QPB; ++q) {
      const float s00 = RLF(q0.x, q), s01 = RLF(q0.y, q), s02 = RLF(q0.z, q), s03 = RLF(q0.w, q);
      const float s10 = RLF(q1.x, q), s11 = RLF(q1.y, q), s12 = RLF(q1.z, q), s13 = RLF(q1.w, q);
      const float s20 = RLF(q2.x, q), s21 = RLF(q2.y, q), s22 = RLF(q2.z, q), s23 = RLF(q2.w, q);
      const float s30 = RLF(q3.x, q), s31 = RLF(q3.y, q), s32 = RLF(q3.z, q), s33 = RLF(q3.w, q);
      const float sxx = RLF(xxq, q);
      const float sth = RLF(thrF, q);
      float a0 = s00 * cc0.x;
      a0 = fmaf(s01, cc0.y, a0); a0 = fmaf(s02, cc0.z, a0); a0 = fmaf(s03, cc0.w, a0);
      a0 = fmaf(s10, cc1.x, a0); a0 = fmaf(s11, cc1.y, a0); a0 = fmaf(s12, cc1.z, a0);
      a0 = fmaf(s13, cc1.w, a0);
      float a1 = s20 * cc2.x;
      a1 = fmaf(s21, cc2.y, a1); a1 = fmaf(s22, cc2.z, a1); a1 = fmaf(s23, cc2.w, a1);
      a1 = fmaf(s30, cc3.x, a1); a1 = fmaf(s31, cc3.y, a1); a1 = fmaf(s32, cc3.z, a1);
      a1 = fmaf(s33, cc3.w, a1);
      const float d = fmaf(-2.0f, a0 + a1, sxx) + cxx;
      bool pend = d <= sth;
      unsigned long long pm = __ballot(pend);
      if (__builtin_expect(pm != 0, 0)) {
        const int L = (seg << 6) | q;
        unsigned swc = __builtin_amdgcn_readlane((unsigned)wcv, q);
        while (true) {
          const unsigned cnt = (unsigned)__popcll(pm);
          if (swc + cnt <= (unsigned)CAP) {
            if (pend) {
              const unsigned r = laneRank(pm);
              logbuf[(size_t)L * CAPP + swc + r] =
                  ((unsigned long long)floatToKey(d) << 32) | gidx;
            }
            if (lane == q) wcv = (int)(swc + cnt);
            break;
          }
          // Overflow (rare): fill remaining room, then single-lane compact.
          const unsigned room = (unsigned)CAP - swc;
          const unsigned r = laneRank(pm);
          if (pend && r < room) {
            logbuf[(size_t)L * CAPP + swc + r] =
                ((unsigned long long)floatToKey(d) << 32) | gidx;
            pend = false;
          }
          asm volatile("s_waitcnt lgkmcnt(0)" ::: "memory");
          pm = __ballot(pend);
          if (pend && laneRank(pm) == 0) {
            serial_compact(&logbuf[(size_t)L * CAPP], CAP, &wcarr[L], &thrv[L]);
          }
          asm volatile("s_waitcnt lgkmcnt(0)" ::: "memory");
          const float nth = thrv[L];
          swc = wcarr[L];
          if (lane == q) { thrF = nth; wcv = (int)swc; }
          pend = pend && (d <= nth);
          pm = __ballot(pend);
          if (!pm) break;
        }
      }
    }
#undef RLF
    if (T + 1 < 32) { cc0 = n0; cc1 = n1; cc2 = n2; cc3 = n3; cxx = nx; }
  }
  wc = wcv;
  __syncthreads();

  // ===== Phase 2: VERIFIED tail — rekey, sort, merge (byte-identical R15) =====
  const int brow = b * NP;
  for (int i = 0; i < wc; ++i) {
    const unsigned e = (unsigned)mylog[i] & 0x1FFFu;
    const float4* cp = reinterpret_cast<const float4*>(x) + (size_t)(brow + e) * 4;
    const float4 c0 = cp[0], c1 = cp[1], c2 = cp[2], c3 = cp[3];
    const float dot = dot16_ref(q0, q1, q2, q3, c0, c1, c2, c3);
    const float dref = dref_combine(xxq, dot, xxf[brow + e]);
    mylog[i] = ((unsigned long long)floatToKey(dref) << 13) | (unsigned long long)e;
  }
  for (int i = 1; i < wc; ++i) {
    unsigned long long key = mylog[i];
    int j = i - 1;
    while (j >= 0 && mylog[j] > key) {
      mylog[j + 1] = mylog[j];
      --j;
    }
    mylog[j + 1] = key;
  }
  mylog[wc] = ~0ULL;
  __syncthreads();

  if (tid < QPB) {
    const int mq = blockIdx.x * QPB + tid;
    unsigned long long h0 = logbuf[(size_t)(0 * QPB + tid) * CAPP + 0];
    unsigned long long h1 = logbuf[(size_t)(1 * QPB + tid) * CAPP + 0];
    unsigned long long h2 = logbuf[(size_t)(2 * QPB + tid) * CAPP + 0];
    unsigned long long h3 = logbuf[(size_t)(3 * QPB + tid) * CAPP + 0];
    int p0 = 1, p1 = 1, p2 = 1, p3 = 1;
    float* dst = oidx + (size_t)mq * KK;
#pragma unroll 1
    for (int r = 0; r < KK; ++r) {
      const unsigned long long m01 = (h0 < h1) ? h0 : h1;
      const unsigned long long m23 = (h2 < h3) ? h2 : h3;
      const unsigned long long m = (m01 < m23) ? m01 : m23;
      dst[r] = (float)(unsigned)(m & 0x1FFFull);
      if (m == h0)      h0 = logbuf[(size_t)(0 * QPB + tid) * CAPP + (p0++)];
      else if (m == h1) h1 = logbuf[(size_t)(1 * QPB + tid) * CAPP + (p1++)];
      else if (m == h2) h2 = logbuf[(size_t)(2 * QPB + tid) * CAPP + (p2++)];
      else              h3 = logbuf[(size_t)(3 * QPB + tid) * CAPP + (p3++)];
    }
  }
}

extern "C" void kernel_launch(void* const* d_in, const int* in_sizes, int n_in,
                              void* d_out, int out_size, void* d_ws, size_t ws_size,
                              hipStream_t stream) {
  const float* x = (const float*)d_in[0];
  float* out = (float*)d_out;
  float* xxf = (float*)d_ws;

  hipLaunchKernelGGL(knn_prep_kernel, dim3(NB * NP / 256), dim3(256), 0, stream,
                     x, out, xxf);
  hipLaunchKernelGGL(knn_main_kernel, dim3(NB * NP / QPB), dim3(TPB), 0, stream,
                     x, xxf, out + XOFF);
}